// Round 15
// baseline (187.659 us; speedup 1.0000x reference)
//
#include <hip/hip_runtime.h>
#include <cstdint>
#include <cstddef>

#define Bc 8
#define Sc 2048
#define Dc 512

typedef float f32x4 __attribute__((ext_vector_type(4)));
typedef __bf16 bf16x8 __attribute__((ext_vector_type(8)));
typedef __bf16 bf16x4 __attribute__((ext_vector_type(4)));

__device__ __forceinline__ void gload_lds16(const void* g, void* l) {
    __builtin_amdgcn_global_load_lds((const __attribute__((address_space(1))) void*)g,
                                     (__attribute__((address_space(3))) void*)l, 16, 0, 0);
}

__device__ __forceinline__ f32x4 mfma16x16x32(bf16x8 a, bf16x8 b, f32x4 c) {
    return __builtin_amdgcn_mfma_f32_16x16x32_bf16(a, b, c, 0, 0, 0);
}

// ---- convert W_in / W_out to bf16 (512*512 each) ----
__global__ void k_convert_w(const float* __restrict__ wi, const float* __restrict__ wo,
                            __bf16* __restrict__ wib, __bf16* __restrict__ wob) {
    int i = blockIdx.x * 256 + threadIdx.x;   // grid sized exactly Dc*Dc/256
    wib[i] = (__bf16)wi[i];
    wob[i] = (__bf16)wo[i];
}

// ---- scores kernel v2: 128x128x512 tile, DOUBLE-BUFFERED counted-vmcnt K-loop
//      (R12 PV's proven schedule): stage(t+1) overlaps MFMA(t); vmcnt(0) after
//      MFMA certifies the 8 stage ops (only VMEM in loop). Emits E bf16 + stats.
//      XCD-batch-pinned. ----
__global__ __launch_bounds__(256) void k_scores(
        const __bf16* __restrict__ c, __bf16* __restrict__ Ebuf,
        float2* __restrict__ stats)
{
    __shared__ alignas(16) char smem[65536];      // 2 x (As 16K + Bs 16K); epilogue Es overlays
    const int tid  = threadIdx.x;
    const int wave = tid >> 6, lane = tid & 63;
    const int waveM = wave >> 1, waveN = wave & 1;
    const int bid  = blockIdx.x;
    const int bz   = bid & 7;
    const int col0 = ((bid >> 3) & 15) * 128;
    const int row0 = (bid >> 7) * 128;
    const __bf16* A  = c + (size_t)bz * Sc * Dc;

    f32x4 acc[4][4] = {};

    auto stage = [&](char* buf, int k0) {         // 8 gload_lds / thread
        __bf16* As = (__bf16*)buf;
        __bf16* Bs = (__bf16*)(buf + 16384);
        #pragma unroll
        for (int i = 0; i < 4; ++i) {
            int flat = i * 2048 + wave * 512 + lane * 8;
            int r  = flat >> 6;
            int cc = (flat >> 3) & 7;
            int gc = (cc ^ (r & 7)) << 3;
            gload_lds16(A + (size_t)(row0 + r) * Dc + k0 + gc, As + i * 2048 + wave * 512);
            gload_lds16(A + (size_t)(col0 + r) * Dc + k0 + gc, Bs + i * 2048 + wave * 512);
        }
    };

    // prologue: buf0 <- k=0
    stage(smem, 0);
    asm volatile("s_waitcnt vmcnt(0)" ::: "memory");
    __builtin_amdgcn_sched_barrier(0);
    __builtin_amdgcn_s_barrier();
    __builtin_amdgcn_sched_barrier(0);

    #pragma unroll
    for (int t = 0; t < 8; ++t) {                 // K = 8 x 64
        char* cur = smem + ((t & 1) ? 32768 : 0);
        char* nxt = smem + ((t & 1) ? 0 : 32768);
        __bf16* As = (__bf16*)cur;
        __bf16* Bs = (__bf16*)(cur + 16384);
        bf16x8 av[4][2], bv[2][4];
        #pragma unroll
        for (int ks = 0; ks < 2; ++ks) {
            const int kc = ks * 4 + (lane >> 4);
            #pragma unroll
            for (int mi = 0; mi < 4; ++mi) {
                int r = waveM * 64 + mi * 16 + (lane & 15);
                av[mi][ks] = *(const bf16x8*)&As[r * 64 + ((kc ^ (r & 7)) << 3)];
            }
            #pragma unroll
            for (int ni = 0; ni < 4; ++ni) {
                int r = waveN * 64 + ni * 16 + (lane & 15);
                bv[ks][ni] = *(const bf16x8*)&Bs[r * 64 + ((kc ^ (r & 7)) << 3)];
            }
        }
        if (t + 1 < 8) {
            stage(nxt, (t + 1) * 64);             // drains under MFMA
            __builtin_amdgcn_sched_barrier(0);
        }
        #pragma unroll
        for (int ks = 0; ks < 2; ++ks)
            #pragma unroll
            for (int mi = 0; mi < 4; ++mi)
                #pragma unroll
                for (int ni = 0; ni < 4; ++ni)
                    acc[mi][ni] = mfma16x16x32(av[mi][ks], bv[ks][ni], acc[mi][ni]);
        if (t + 1 < 8) {
            asm volatile("s_waitcnt vmcnt(0)" ::: "memory");  // own 8 stage ops done
            __builtin_amdgcn_sched_barrier(0);
            __builtin_amdgcn_s_barrier();                     // all staged -> next iter reads
            __builtin_amdgcn_sched_barrier(0);
        }
    }

    // epilogue: per (row, this wave's 64-col half): m = max, E = exp(s-m), z = sum E.
    // Es overlays smem (all waves are past the t=6 barrier; buf1 was the last read).
    const int rb = (lane >> 4) << 2;
    const int cb = lane & 15;
    __bf16* Es = (__bf16*)smem;                   // [128][136] bf16
    #pragma unroll
    for (int mi = 0; mi < 4; ++mi)
        #pragma unroll
        for (int rr = 0; rr < 4; ++rr) {
            float mx = fmaxf(fmaxf(acc[mi][0][rr], acc[mi][1][rr]),
                             fmaxf(acc[mi][2][rr], acc[mi][3][rr]));
            #pragma unroll
            for (int off = 1; off < 16; off <<= 1) mx = fmaxf(mx, __shfl_xor(mx, off));
            const int rloc = waveM * 64 + mi * 16 + rb + rr;
            float zs = 0.f;
            #pragma unroll
            for (int ni = 0; ni < 4; ++ni) {
                float e = __expf(acc[mi][ni][rr] - mx);
                zs += e;
                Es[rloc * 136 + waveN * 64 + ni * 16 + cb] = (__bf16)e;
            }
            #pragma unroll
            for (int off = 1; off < 16; off <<= 1) zs += __shfl_xor(zs, off);
            if ((lane & 15) == 0)
                stats[((size_t)bz * Sc + row0 + rloc) * 32 + (col0 >> 6) + waveN] =
                    make_float2(mx, zs);
        }
    __syncthreads();
    #pragma unroll
    for (int p = 0; p < 8; ++p) {
        int r  = p * 16 + (tid >> 4);
        int cc = (tid & 15) * 8;
        bf16x8 v = *(const bf16x8*)&Es[r * 136 + cc];
        *(bf16x8*)&Ebuf[((size_t)bz * Sc + row0 + r) * Sc + col0 + cc] = v;
    }
}

// ---- combine per-64-tile stats -> per-(row,tile) correction exp(m_i - M)/Z ----
__global__ __launch_bounds__(256) void k_combine(const float2* __restrict__ stats,
                                                 float* __restrict__ corrTab) {
    int r = blockIdx.x * 256 + threadIdx.x;   // grid = 16384/256
    float2 s[32];
    #pragma unroll
    for (int i = 0; i < 32; ++i) s[i] = stats[(size_t)r * 32 + i];
    float M = s[0].x;
    #pragma unroll
    for (int i = 1; i < 32; ++i) M = fmaxf(M, s[i].x);
    float Z = 0.f;
    #pragma unroll
    for (int i = 0; i < 32; ++i) Z += s[i].y * __expf(s[i].x - M);
    float zi = 1.f / Z;
    #pragma unroll
    for (int i = 0; i < 32; ++i) corrTab[(size_t)r * 32 + i] = __expf(s[i].x - M) * zi;
}

// ---- fused PV v10 (unchanged from R12): 64 rows x 512 D-cols, 512 thr, 8 waves,
//      72 KiB LDS single-buffered, grid 256 (1 block/CU, XCD-batch-pinned),
//      counted-vmcnt schedule. ----
__global__ __launch_bounds__(512) void k_pv_fused(
        const __bf16* __restrict__ Ebuf,     // E [B][S][S] bf16
        const __bf16* __restrict__ cT,       // [B][D][S]
        const float* __restrict__ corrTab,   // [B*S][32]
        float* __restrict__ attn,            // [B][S][S] fp32 OUTPUT
        __bf16* __restrict__ ctx)            // [B*S][D] tanh(attn @ c)
{
    __shared__ alignas(16) __bf16 As[64 * 64];    //  8 KiB (P tile, swizzled)
    __shared__ alignas(16) __bf16 Bs[512 * 64];   // 64 KiB (cT K-slice)
    const int tid  = threadIdx.x;
    const int wave = tid >> 6, lane = tid & 63;
    const int b    = blockIdx.x & 7;              // == XCD id under %8 round-robin
    const int row0 = (blockIdx.x >> 3) * 64;
    const __bf16* Bt = cT + (size_t)b * Dc * Sc;

    const int ar = tid >> 3;            // 0..63
    const int ac = (tid & 7) * 8;       // 0..56
    const __bf16* erow = Ebuf + ((size_t)b * Sc + row0 + ar) * Sc + ac;
    const float*  crow = corrTab + ((size_t)b * Sc + row0 + ar) * 32;
    float*        prow = attn + ((size_t)b * Sc + row0 + ar) * Sc + ac;
    const int a_addr = ar * 64 + (((ac >> 3) ^ (ar & 7)) << 3);

    f32x4 acc[4][4] = {};               // wave tile: 64 rows x 64 cols
    const int NT = Sc / 64;             // 32 K-tiles

    auto stageB = [&](int kt) {         // [512][64] bf16 = 4096 chunks, 8 / thread
        #pragma unroll
        for (int i = 0; i < 8; ++i) {
            int chunk = i * 512 + tid;
            int r  = chunk >> 3;
            int cc = chunk & 7;
            gload_lds16(Bt + (size_t)r * Sc + kt + ((cc ^ (r & 7)) << 3),
                        Bs + (size_t)chunk * 8);
        }
    };

    bf16x8 e = *(const bf16x8*)&erow[0];
    float  cf = crow[0];
    f32x4 p0, p1;
    #pragma unroll
    for (int j = 0; j < 4; ++j) { p0[j] = (float)e[j] * cf; p1[j] = (float)e[4 + j] * cf; }
    {
        bf16x8 pb;
        #pragma unroll
        for (int j = 0; j < 4; ++j) { pb[j] = (__bf16)p0[j]; pb[4 + j] = (__bf16)p1[j]; }
        *(bf16x8*)&As[a_addr] = pb;                          // lgkm +1
    }
    stageB(0);                                               // vm +8 (oldest)
    __builtin_amdgcn_sched_barrier(0);                       // pin younger vmem after stage
    *(f32x4*)&prow[0] = p0;                                  // vm +1
    *(f32x4*)&prow[4] = p1;                                  // vm +1
    e  = *(const bf16x8*)&erow[64];                          // vm +1
    cf = crow[1];                                            // vm +1
    asm volatile("s_waitcnt vmcnt(4) lgkmcnt(0)" ::: "memory");
    __builtin_amdgcn_sched_barrier(0);
    __builtin_amdgcn_s_barrier();

    for (int t = 0; t < NT; ++t) {
        bf16x8 av[4][2], bv[2][4];
        #pragma unroll
        for (int ks = 0; ks < 2; ++ks) {
            const int kc = ks * 4 + (lane >> 4);
            #pragma unroll
            for (int mi = 0; mi < 4; ++mi) {
                int r = mi * 16 + (lane & 15);
                av[mi][ks] = *(const bf16x8*)&As[r * 64 + ((kc ^ (r & 7)) << 3)];
            }
            #pragma unroll
            for (int ni = 0; ni < 4; ++ni) {
                int r = wave * 64 + ni * 16 + (lane & 15);
                bv[ks][ni] = *(const bf16x8*)&Bs[r * 64 + ((kc ^ (r & 7)) << 3)];
            }
        }
        asm volatile("s_waitcnt lgkmcnt(0)" ::: "memory");
        __builtin_amdgcn_sched_barrier(0);
        __builtin_amdgcn_s_barrier();

        if (t + 1 < NT) {
            stageB((t + 1) * 64);                            // vm +8
            __builtin_amdgcn_sched_barrier(0);
            f32x4 q0, q1;
            #pragma unroll
            for (int j = 0; j < 4; ++j) {
                q0[j] = (float)e[j] * cf; q1[j] = (float)e[4 + j] * cf;
            }
            bf16x8 pb;
            #pragma unroll
            for (int j = 0; j < 4; ++j) { pb[j] = (__bf16)q0[j]; pb[4 + j] = (__bf16)q1[j]; }
            *(bf16x8*)&As[a_addr] = pb;                      // lgkm +1
            *(f32x4*)&prow[(t + 1) * 64]     = q0;           // vm +1
            *(f32x4*)&prow[(t + 1) * 64 + 4] = q1;           // vm +1
            if (t + 2 < NT) {
                e  = *(const bf16x8*)&erow[(t + 2) * 64];    // vm +1
                cf = crow[t + 2];                            // vm +1
            }
        }

        #pragma unroll
        for (int ks = 0; ks < 2; ++ks)
            #pragma unroll
            for (int mi = 0; mi < 4; ++mi)
                #pragma unroll
                for (int ni = 0; ni < 4; ++ni)
                    acc[mi][ni] = mfma16x16x32(av[mi][ks], bv[ks][ni], acc[mi][ni]);

        if (t + 1 < NT) {
            if (t + 2 < NT)
                asm volatile("s_waitcnt vmcnt(4) lgkmcnt(0)" ::: "memory");
            else
                asm volatile("s_waitcnt vmcnt(2) lgkmcnt(0)" ::: "memory");
            __builtin_amdgcn_sched_barrier(0);
            __builtin_amdgcn_s_barrier();
        }
    }

    const int rb = (lane >> 4) << 2;
    const int cb = lane & 15;
    #pragma unroll
    for (int mi = 0; mi < 4; ++mi)
        #pragma unroll
        for (int ni = 0; ni < 4; ++ni) {
            int gr = row0 + mi * 16 + rb;
            int gc = wave * 64 + ni * 16 + cb;
            #pragma unroll
            for (int rr = 0; rr < 4; ++rr)
                ctx[(size_t)(b * Sc + gr + rr) * Dc + gc] = (__bf16)tanhf(acc[mi][ni][rr]);
        }
}

// ---- bf16 GEMM (out-projection): C fp32 = A[M,K] * Bt[N,K]^T, 128x128x64 ----
__global__ __launch_bounds__(256) void k_gemm_bf16(
        const __bf16* __restrict__ A, const __bf16* __restrict__ Bt,
        float* __restrict__ C, int lda, int ldb, int ldc, int K)
{
    __shared__ alignas(16) __bf16 smem[2 * 128 * 64];
    __bf16* As = smem;
    __bf16* Bs = smem + 128 * 64;
    const int tid  = threadIdx.x;
    const int wave = tid >> 6, lane = tid & 63;
    const int waveM = wave >> 1, waveN = wave & 1;
    const int row0 = blockIdx.y * 128;
    const int col0 = blockIdx.x * 128;

    f32x4 acc[4][4] = {};

    for (int k0 = 0; k0 < K; k0 += 64) {
        #pragma unroll
        for (int i = 0; i < 4; ++i) {
            int flat = i * 2048 + wave * 512 + lane * 8;
            int r  = flat >> 6;
            int cc = (flat >> 3) & 7;
            int gc = (cc ^ (r & 7)) << 3;
            gload_lds16(A  + (size_t)(row0 + r) * lda + k0 + gc, As + i * 2048 + wave * 512);
            gload_lds16(Bt + (size_t)(col0 + r) * ldb + k0 + gc, Bs + i * 2048 + wave * 512);
        }
        __syncthreads();
        #pragma unroll
        for (int ks = 0; ks < 2; ++ks) {
            const int kc = ks * 4 + (lane >> 4);
            bf16x8 av[4], bv[4];
            #pragma unroll
            for (int mi = 0; mi < 4; ++mi) {
                int r = waveM * 64 + mi * 16 + (lane & 15);
                av[mi] = *(const bf16x8*)&As[r * 64 + ((kc ^ (r & 7)) << 3)];
            }
            #pragma unroll
            for (int ni = 0; ni < 4; ++ni) {
                int r = waveN * 64 + ni * 16 + (lane & 15);
                bv[ni] = *(const bf16x8*)&Bs[r * 64 + ((kc ^ (r & 7)) << 3)];
            }
            #pragma unroll
            for (int mi = 0; mi < 4; ++mi)
                #pragma unroll
                for (int ni = 0; ni < 4; ++ni)
                    acc[mi][ni] = mfma16x16x32(av[mi], bv[ni], acc[mi][ni]);
        }
        __syncthreads();
    }

    const int rb = (lane >> 4) << 2;
    const int cb = lane & 15;
    #pragma unroll
    for (int mi = 0; mi < 4; ++mi)
        #pragma unroll
        for (int ni = 0; ni < 4; ++ni) {
            int gr = row0 + waveM * 64 + mi * 16 + rb;
            int gc = col0 + waveN * 64 + ni * 16 + cb;
            #pragma unroll
            for (int rr = 0; rr < 4; ++rr)
                C[(size_t)(gr + rr) * ldc + gc] = acc[mi][ni][rr];
        }
}

// ---- fp32-A, bf16-B GEMM (c-projection): writes bf16 C and bf16 C^T ----
__global__ __launch_bounds__(256) void k_cproj(
        const float* __restrict__ A, const __bf16* __restrict__ Bt,
        __bf16* __restrict__ Cb, __bf16* __restrict__ CTb)
{
    __shared__ alignas(16) char smem[49152];
    float*  Asf = (float*)smem;              // [128][64] fp32 (32 KiB)
    __bf16* Bs  = (__bf16*)(smem + 32768);   // [128][64] bf16 (16 KiB)
    const int tid  = threadIdx.x;
    const int wave = tid >> 6, lane = tid & 63;
    const int waveM = wave >> 1, waveN = wave & 1;
    const int row0 = blockIdx.y * 128;
    const int col0 = blockIdx.x * 128;

    f32x4 acc[4][4] = {};

    for (int k0 = 0; k0 < Dc; k0 += 64) {
        #pragma unroll
        for (int i = 0; i < 8; ++i) {        // A fp32: 16 chunks/row of 4 floats
            int flat = i * 1024 + wave * 256 + lane * 4;
            int r  = flat >> 6;
            int cc = (flat >> 2) & 15;
            int gc = (cc ^ (r & 15)) << 2;
            gload_lds16(A + (size_t)(row0 + r) * Dc + k0 + gc, Asf + i * 1024 + wave * 256);
        }
        #pragma unroll
        for (int i = 0; i < 4; ++i) {        // B bf16: 8 chunks/row of 8 elems
            int flat = i * 2048 + wave * 512 + lane * 8;
            int r  = flat >> 6;
            int cc = (flat >> 3) & 7;
            int gc = (cc ^ (r & 7)) << 3;
            gload_lds16(Bt + (size_t)(col0 + r) * Dc + k0 + gc, Bs + i * 2048 + wave * 512);
        }
        __syncthreads();
        #pragma unroll
        for (int ks = 0; ks < 2; ++ks) {
            const int kc8 = ks * 4 + (lane >> 4);
            const int kc4 = kc8 << 1;
            bf16x8 av[4], bv[4];
            #pragma unroll
            for (int mi = 0; mi < 4; ++mi) {
                int r  = waveM * 64 + mi * 16 + (lane & 15);
                int r4 = r & 15;
                f32x4 lo = *(const f32x4*)&Asf[r * 64 + (((kc4    ) ^ r4) << 2)];
                f32x4 hi = *(const f32x4*)&Asf[r * 64 + (((kc4 + 1) ^ r4) << 2)];
                bf16x8 a;
                a[0] = (__bf16)lo[0]; a[1] = (__bf16)lo[1]; a[2] = (__bf16)lo[2]; a[3] = (__bf16)lo[3];
                a[4] = (__bf16)hi[0]; a[5] = (__bf16)hi[1]; a[6] = (__bf16)hi[2]; a[7] = (__bf16)hi[3];
                av[mi] = a;
            }
            #pragma unroll
            for (int ni = 0; ni < 4; ++ni) {
                int r = waveN * 64 + ni * 16 + (lane & 15);
                bv[ni] = *(const bf16x8*)&Bs[r * 64 + ((kc8 ^ (r & 7)) << 3)];
            }
            #pragma unroll
            for (int mi = 0; mi < 4; ++mi)
                #pragma unroll
                for (int ni = 0; ni < 4; ++ni)
                    acc[mi][ni] = mfma16x16x32(av[mi], bv[ni], acc[mi][ni]);
        }
        __syncthreads();
    }

    const int rb = (lane >> 4) << 2;
    const int cb = lane & 15;
    __bf16* T = (__bf16*)smem;               // [128][136] transpose staging
    #pragma unroll
    for (int mi = 0; mi < 4; ++mi)
        #pragma unroll
        for (int ni = 0; ni < 4; ++ni) {
            int lr = waveM * 64 + mi * 16 + rb;
            int lc = waveN * 64 + ni * 16 + cb;
            #pragma unroll
            for (int rr = 0; rr < 4; ++rr) {
                __bf16 h = (__bf16)acc[mi][ni][rr];
                Cb[(size_t)(row0 + lr + rr) * Dc + col0 + lc] = h;
                T[lc * 136 + lr + rr] = h;
            }
        }
    __syncthreads();
    const int bb = row0 >> 11;               // batch = global row / 2048
    const int s0 = row0 & 2047;
    #pragma unroll
    for (int i = 0; i < 8; ++i) {
        int n  = i * 16 + (tid >> 4);
        int mo = (tid & 15) * 8;
        bf16x8 v = *(const bf16x8*)&T[n * 136 + mo];
        *(bf16x8*)&CTb[(size_t)bb * Dc * Sc + (size_t)(col0 + n) * Sc + s0 + mo] = v;
    }
}

extern "C" void kernel_launch(void* const* d_in, const int* in_sizes, int n_in,
                              void* d_out, int out_size, void* d_ws, size_t ws_size,
                              hipStream_t stream)
{
    (void)in_sizes; (void)n_in; (void)out_size; (void)ws_size;
    const float* context = (const float*)d_in[0];
    const float* W_in    = (const float*)d_in[1];
    const float* W_out   = (const float*)d_in[2];
    float* out  = (float*)d_out;
    float* attn = out + (size_t)Bc * Sc * Dc;       // [B,S,S] fp32 output (written by PV)

    char* ws = (char*)d_ws;
    __bf16* c_bf    = (__bf16*)ws;                                 // [B*S, D]; later tanh(ctx)
    __bf16* cT_bf   = (__bf16*)(ws + 16777216);                    // [B, D, S]
    __bf16* wi_bf   = (__bf16*)(ws + 33554432);
    __bf16* wo_bf   = (__bf16*)(ws + 34078720);
    float2* stats   = (float2*)(ws + 34603008);                    // [B*S][32] {m, sumE}
    float*  corrTab = (float*)(ws + 38797312);                     // [B*S][32]
    __bf16* Ebuf    = (__bf16*)(ws + 40894464);                    // [B][S][S] bf16

    // W -> bf16
    k_convert_w<<<dim3(Dc * Dc / 256), 256, 0, stream>>>(W_in, W_out, wi_bf, wo_bf);

    // c = context @ W_in^T  (also emits c^T)
    k_cproj<<<dim3(Dc / 128, (Bc * Sc) / 128), 256, 0, stream>>>(context, wi_bf, c_bf, cT_bf);

    // E = exp(scores - m_tile) bf16 + per-64-tile stats (XCD-batch-pinned)
    k_scores<<<dim3(Bc * 16 * 16), 256, 0, stream>>>(c_bf, Ebuf, stats);

    // per-(row,tile) correction factors exp(m_i - M)/Z
    k_combine<<<dim3(Bc * Sc / 256), 256, 0, stream>>>(stats, corrTab);

    // PV: attn = E*corr (fp32 -> output) ; ctx = tanh(attn @ c) bf16
    k_pv_fused<<<dim3((Sc / 64) * Bc), 512, 0, stream>>>(Ebuf, cT_bf, corrTab, attn, c_bf);

    // out = tanh(ctx) @ W_out^T
    k_gemm_bf16<<<dim3(Dc / 128, (Bc * Sc) / 128, 1), 256, 0, stream>>>(
        c_bf, wo_bf, out, Dc, Dc, Dc, Dc);
}

// Round 16
// 182.381 us; speedup vs baseline: 1.0289x; 1.0289x over previous
//
#include <hip/hip_runtime.h>
#include <cstdint>
#include <cstddef>

#define Bc 8
#define Sc 2048
#define Dc 512

typedef float f32x4 __attribute__((ext_vector_type(4)));
typedef __bf16 bf16x8 __attribute__((ext_vector_type(8)));
typedef __bf16 bf16x4 __attribute__((ext_vector_type(4)));

__device__ __forceinline__ void gload_lds16(const void* g, void* l) {
    __builtin_amdgcn_global_load_lds((const __attribute__((address_space(1))) void*)g,
                                     (__attribute__((address_space(3))) void*)l, 16, 0, 0);
}

__device__ __forceinline__ f32x4 mfma16x16x32(bf16x8 a, bf16x8 b, f32x4 c) {
    return __builtin_amdgcn_mfma_f32_16x16x32_bf16(a, b, c, 0, 0, 0);
}

// ---- convert W_in / W_out to bf16 (512*512 each) ----
__global__ void k_convert_w(const float* __restrict__ wi, const float* __restrict__ wo,
                            __bf16* __restrict__ wib, __bf16* __restrict__ wob) {
    int i = blockIdx.x * 256 + threadIdx.x;   // grid sized exactly Dc*Dc/256
    wib[i] = (__bf16)wi[i];
    wob[i] = (__bf16)wo[i];
}

// ---- scores kernel (R12 single-buffer variant): 128x128x512 tile; emits
//      E = exp(s - m_tile) bf16 + per-(row, 64-col-tile) stats {m, sum E}.
//      XCD-batch-pinned. ----
__global__ __launch_bounds__(256) void k_scores(
        const __bf16* __restrict__ c, __bf16* __restrict__ Ebuf,
        float2* __restrict__ stats)
{
    __shared__ alignas(16) char smem[34816];
    __bf16* As = (__bf16*)smem;
    __bf16* Bs = (__bf16*)(smem + 16384);
    const int tid  = threadIdx.x;
    const int wave = tid >> 6, lane = tid & 63;
    const int waveM = wave >> 1, waveN = wave & 1;
    const int bid  = blockIdx.x;
    const int bz   = bid & 7;
    const int col0 = ((bid >> 3) & 15) * 128;
    const int row0 = (bid >> 7) * 128;
    const __bf16* A  = c + (size_t)bz * Sc * Dc;

    f32x4 acc[4][4] = {};

    for (int k0 = 0; k0 < Dc; k0 += 64) {
        #pragma unroll
        for (int i = 0; i < 4; ++i) {
            int flat = i * 2048 + wave * 512 + lane * 8;
            int r  = flat >> 6;
            int cc = (flat >> 3) & 7;
            int gc = (cc ^ (r & 7)) << 3;
            gload_lds16(A + (size_t)(row0 + r) * Dc + k0 + gc, As + i * 2048 + wave * 512);
            gload_lds16(A + (size_t)(col0 + r) * Dc + k0 + gc, Bs + i * 2048 + wave * 512);
        }
        __syncthreads();
        #pragma unroll
        for (int ks = 0; ks < 2; ++ks) {
            const int kc = ks * 4 + (lane >> 4);
            bf16x8 av[4], bv[4];
            #pragma unroll
            for (int mi = 0; mi < 4; ++mi) {
                int r = waveM * 64 + mi * 16 + (lane & 15);
                av[mi] = *(const bf16x8*)&As[r * 64 + ((kc ^ (r & 7)) << 3)];
            }
            #pragma unroll
            for (int ni = 0; ni < 4; ++ni) {
                int r = waveN * 64 + ni * 16 + (lane & 15);
                bv[ni] = *(const bf16x8*)&Bs[r * 64 + ((kc ^ (r & 7)) << 3)];
            }
            #pragma unroll
            for (int mi = 0; mi < 4; ++mi)
                #pragma unroll
                for (int ni = 0; ni < 4; ++ni)
                    acc[mi][ni] = mfma16x16x32(av[mi], bv[ni], acc[mi][ni]);
        }
        __syncthreads();
    }

    const int rb = (lane >> 4) << 2;
    const int cb = lane & 15;
    __bf16* Es = (__bf16*)smem;                   // [128][136] bf16
    #pragma unroll
    for (int mi = 0; mi < 4; ++mi)
        #pragma unroll
        for (int rr = 0; rr < 4; ++rr) {
            float mx = fmaxf(fmaxf(acc[mi][0][rr], acc[mi][1][rr]),
                             fmaxf(acc[mi][2][rr], acc[mi][3][rr]));
            #pragma unroll
            for (int off = 1; off < 16; off <<= 1) mx = fmaxf(mx, __shfl_xor(mx, off));
            const int rloc = waveM * 64 + mi * 16 + rb + rr;
            float zs = 0.f;
            #pragma unroll
            for (int ni = 0; ni < 4; ++ni) {
                float e = __expf(acc[mi][ni][rr] - mx);
                zs += e;
                Es[rloc * 136 + waveN * 64 + ni * 16 + cb] = (__bf16)e;
            }
            #pragma unroll
            for (int off = 1; off < 16; off <<= 1) zs += __shfl_xor(zs, off);
            if ((lane & 15) == 0)
                stats[((size_t)bz * Sc + row0 + rloc) * 32 + (col0 >> 6) + waveN] =
                    make_float2(mx, zs);
        }
    __syncthreads();
    #pragma unroll
    for (int p = 0; p < 8; ++p) {
        int r  = p * 16 + (tid >> 4);
        int cc = (tid & 15) * 8;
        bf16x8 v = *(const bf16x8*)&Es[r * 136 + cc];
        *(bf16x8*)&Ebuf[((size_t)bz * Sc + row0 + r) * Sc + col0 + cc] = v;
    }
}

// ---- fused PV v11: R12's counted-vmcnt schedule + in-prologue softmax combine.
//      64 rows x 512 D-cols, 512 thr, 8 waves, 72 KiB LDS, grid 256
//      (1 block/CU, XCD-batch-pinned). Each thread reduces its row's 32 stats
//      to {M, 1/Z} in registers; per-tile corr = exp(m_t - M)/Z computed at
//      consumption (replaces the k_combine kernel + corrTab round trip). ----
__global__ __launch_bounds__(512) void k_pv_fused(
        const __bf16* __restrict__ Ebuf,     // E [B][S][S] bf16
        const __bf16* __restrict__ cT,       // [B][D][S]
        const float2* __restrict__ stats,    // [B*S][32] {m, sumE}
        float* __restrict__ attn,            // [B][S][S] fp32 OUTPUT
        __bf16* __restrict__ ctx)            // [B*S][D] tanh(attn @ c)
{
    __shared__ alignas(16) __bf16 As[64 * 64];    //  8 KiB (P tile, swizzled)
    __shared__ alignas(16) __bf16 Bs[512 * 64];   // 64 KiB (cT K-slice)
    const int tid  = threadIdx.x;
    const int wave = tid >> 6, lane = tid & 63;
    const int b    = blockIdx.x & 7;              // == XCD id under %8 round-robin
    const int row0 = (blockIdx.x >> 3) * 64;
    const __bf16* Bt = cT + (size_t)b * Dc * Sc;

    const int ar = tid >> 3;            // 0..63
    const int ac = (tid & 7) * 8;       // 0..56
    const __bf16* erow = Ebuf + ((size_t)b * Sc + row0 + ar) * Sc + ac;
    const float*  srow_stats = (const float*)(stats + ((size_t)b * Sc + row0 + ar) * 32);
    float*        prow = attn + ((size_t)b * Sc + row0 + ar) * Sc + ac;
    const int a_addr = ar * 64 + (((ac >> 3) ^ (ar & 7)) << 3);

    // ---- fused combine: M = max m_i ; Z = sum z_i exp(m_i - M) ; zi = 1/Z ----
    f32x4 sb[16];                       // this row's 32 float2 stats (static-indexed)
    #pragma unroll
    for (int i = 0; i < 16; ++i) sb[i] = *(const f32x4*)&srow_stats[i * 4];
    float M = fmaxf(sb[0][0], sb[0][2]);
    #pragma unroll
    for (int i = 1; i < 16; ++i) M = fmaxf(M, fmaxf(sb[i][0], sb[i][2]));
    float Z = 0.f;
    #pragma unroll
    for (int i = 0; i < 16; ++i)
        Z += sb[i][1] * __expf(sb[i][0] - M) + sb[i][3] * __expf(sb[i][2] - M);
    const float zi = 1.f / Z;

    f32x4 acc[4][4] = {};               // wave tile: 64 rows x 64 cols
    const int NT = Sc / 64;             // 32 K-tiles

    auto stageB = [&](int kt) {         // [512][64] bf16 = 4096 chunks, 8 / thread
        #pragma unroll
        for (int i = 0; i < 8; ++i) {
            int chunk = i * 512 + tid;
            int r  = chunk >> 3;
            int cc = chunk & 7;
            gload_lds16(Bt + (size_t)r * Sc + kt + ((cc ^ (r & 7)) << 3),
                        Bs + (size_t)chunk * 8);
        }
    };

    // ---- prologue: P(0)->As + stage B(0); attn store(0) + E(1) in flight ----
    bf16x8 e = *(const bf16x8*)&erow[0];
    float  cf      = __expf(sb[0][0] - M) * zi;   // corr(0)
    float  sm_next = sb[0][2];                    // m(1), raw (transform at use)
    f32x4 p0, p1;
    #pragma unroll
    for (int j = 0; j < 4; ++j) { p0[j] = (float)e[j] * cf; p1[j] = (float)e[4 + j] * cf; }
    {
        bf16x8 pb;
        #pragma unroll
        for (int j = 0; j < 4; ++j) { pb[j] = (__bf16)p0[j]; pb[4 + j] = (__bf16)p1[j]; }
        *(bf16x8*)&As[a_addr] = pb;                          // lgkm +1
    }
    stageB(0);                                               // vm +8 (oldest)
    __builtin_amdgcn_sched_barrier(0);                       // pin younger vmem after stage
    *(f32x4*)&prow[0] = p0;                                  // vm +1
    *(f32x4*)&prow[4] = p1;                                  // vm +1
    e = *(const bf16x8*)&erow[64];                           // vm +1
    asm volatile("s_waitcnt vmcnt(3) lgkmcnt(0)" ::: "memory");  // 8 stage + As done
    __builtin_amdgcn_sched_barrier(0);
    __builtin_amdgcn_s_barrier();

    for (int t = 0; t < NT; ++t) {
        bf16x8 av[4][2], bv[2][4];
        #pragma unroll
        for (int ks = 0; ks < 2; ++ks) {
            const int kc = ks * 4 + (lane >> 4);
            #pragma unroll
            for (int mi = 0; mi < 4; ++mi) {
                int r = mi * 16 + (lane & 15);
                av[mi][ks] = *(const bf16x8*)&As[r * 64 + ((kc ^ (r & 7)) << 3)];
            }
            #pragma unroll
            for (int ni = 0; ni < 4; ++ni) {
                int r = wave * 64 + ni * 16 + (lane & 15);
                bv[ks][ni] = *(const bf16x8*)&Bs[r * 64 + ((kc ^ (r & 7)) << 3)];
            }
        }
        asm volatile("s_waitcnt lgkmcnt(0)" ::: "memory");
        __builtin_amdgcn_sched_barrier(0);
        __builtin_amdgcn_s_barrier();

        if (t + 1 < NT) {
            stageB((t + 1) * 64);                            // vm +8
            __builtin_amdgcn_sched_barrier(0);
            const float cfv = __expf(sm_next - M) * zi;      // corr(t+1)
            f32x4 q0, q1;
            #pragma unroll
            for (int j = 0; j < 4; ++j) {
                q0[j] = (float)e[j] * cfv; q1[j] = (float)e[4 + j] * cfv;
            }
            bf16x8 pb;
            #pragma unroll
            for (int j = 0; j < 4; ++j) { pb[j] = (__bf16)q0[j]; pb[4 + j] = (__bf16)q1[j]; }
            *(bf16x8*)&As[a_addr] = pb;                      // lgkm +1
            *(f32x4*)&prow[(t + 1) * 64]     = q0;           // vm +1
            *(f32x4*)&prow[(t + 1) * 64 + 4] = q1;           // vm +1
            if (t + 2 < NT) {
                e       = *(const bf16x8*)&erow[(t + 2) * 64];   // vm +1
                sm_next = srow_stats[(t + 2) * 2];               // vm +1 (m, raw)
            }
        }

        #pragma unroll
        for (int ks = 0; ks < 2; ++ks)
            #pragma unroll
            for (int mi = 0; mi < 4; ++mi)
                #pragma unroll
                for (int ni = 0; ni < 4; ++ni)
                    acc[mi][ni] = mfma16x16x32(av[mi][ks], bv[ks][ni], acc[mi][ni]);

        if (t + 1 < NT) {
            if (t + 2 < NT)
                asm volatile("s_waitcnt vmcnt(4) lgkmcnt(0)" ::: "memory");
            else
                asm volatile("s_waitcnt vmcnt(2) lgkmcnt(0)" ::: "memory");
            __builtin_amdgcn_sched_barrier(0);
            __builtin_amdgcn_s_barrier();
        }
    }

    const int rb = (lane >> 4) << 2;
    const int cb = lane & 15;
    #pragma unroll
    for (int mi = 0; mi < 4; ++mi)
        #pragma unroll
        for (int ni = 0; ni < 4; ++ni) {
            int gr = row0 + mi * 16 + rb;
            int gc = wave * 64 + ni * 16 + cb;
            #pragma unroll
            for (int rr = 0; rr < 4; ++rr)
                ctx[(size_t)(b * Sc + gr + rr) * Dc + gc] = (__bf16)tanhf(acc[mi][ni][rr]);
        }
}

// ---- bf16 GEMM (out-projection): C fp32 = A[M,K] * Bt[N,K]^T, 128x128x64 ----
__global__ __launch_bounds__(256) void k_gemm_bf16(
        const __bf16* __restrict__ A, const __bf16* __restrict__ Bt,
        float* __restrict__ C, int lda, int ldb, int ldc, int K)
{
    __shared__ alignas(16) __bf16 smem[2 * 128 * 64];
    __bf16* As = smem;
    __bf16* Bs = smem + 128 * 64;
    const int tid  = threadIdx.x;
    const int wave = tid >> 6, lane = tid & 63;
    const int waveM = wave >> 1, waveN = wave & 1;
    const int row0 = blockIdx.y * 128;
    const int col0 = blockIdx.x * 128;

    f32x4 acc[4][4] = {};

    for (int k0 = 0; k0 < K; k0 += 64) {
        #pragma unroll
        for (int i = 0; i < 4; ++i) {
            int flat = i * 2048 + wave * 512 + lane * 8;
            int r  = flat >> 6;
            int cc = (flat >> 3) & 7;
            int gc = (cc ^ (r & 7)) << 3;
            gload_lds16(A  + (size_t)(row0 + r) * lda + k0 + gc, As + i * 2048 + wave * 512);
            gload_lds16(Bt + (size_t)(col0 + r) * ldb + k0 + gc, Bs + i * 2048 + wave * 512);
        }
        __syncthreads();
        #pragma unroll
        for (int ks = 0; ks < 2; ++ks) {
            const int kc = ks * 4 + (lane >> 4);
            bf16x8 av[4], bv[4];
            #pragma unroll
            for (int mi = 0; mi < 4; ++mi) {
                int r = waveM * 64 + mi * 16 + (lane & 15);
                av[mi] = *(const bf16x8*)&As[r * 64 + ((kc ^ (r & 7)) << 3)];
            }
            #pragma unroll
            for (int ni = 0; ni < 4; ++ni) {
                int r = waveN * 64 + ni * 16 + (lane & 15);
                bv[ni] = *(const bf16x8*)&Bs[r * 64 + ((kc ^ (r & 7)) << 3)];
            }
            #pragma unroll
            for (int mi = 0; mi < 4; ++mi)
                #pragma unroll
                for (int ni = 0; ni < 4; ++ni)
                    acc[mi][ni] = mfma16x16x32(av[mi], bv[ni], acc[mi][ni]);
        }
        __syncthreads();
    }

    const int rb = (lane >> 4) << 2;
    const int cb = lane & 15;
    #pragma unroll
    for (int mi = 0; mi < 4; ++mi)
        #pragma unroll
        for (int ni = 0; ni < 4; ++ni) {
            int gr = row0 + waveM * 64 + mi * 16 + rb;
            int gc = col0 + waveN * 64 + ni * 16 + cb;
            #pragma unroll
            for (int rr = 0; rr < 4; ++rr)
                C[(size_t)(gr + rr) * ldc + gc] = acc[mi][ni][rr];
        }
}

// ---- fp32-A, bf16-B GEMM (c-projection): writes bf16 C and bf16 C^T ----
__global__ __launch_bounds__(256) void k_cproj(
        const float* __restrict__ A, const __bf16* __restrict__ Bt,
        __bf16* __restrict__ Cb, __bf16* __restrict__ CTb)
{
    __shared__ alignas(16) char smem[49152];
    float*  Asf = (float*)smem;              // [128][64] fp32 (32 KiB)
    __bf16* Bs  = (__bf16*)(smem + 32768);   // [128][64] bf16 (16 KiB)
    const int tid  = threadIdx.x;
    const int wave = tid >> 6, lane = tid & 63;
    const int waveM = wave >> 1, waveN = wave & 1;
    const int row0 = blockIdx.y * 128;
    const int col0 = blockIdx.x * 128;

    f32x4 acc[4][4] = {};

    for (int k0 = 0; k0 < Dc; k0 += 64) {
        #pragma unroll
        for (int i = 0; i < 8; ++i) {        // A fp32: 16 chunks/row of 4 floats
            int flat = i * 1024 + wave * 256 + lane * 4;
            int r  = flat >> 6;
            int cc = (flat >> 2) & 15;
            int gc = (cc ^ (r & 15)) << 2;
            gload_lds16(A + (size_t)(row0 + r) * Dc + k0 + gc, Asf + i * 1024 + wave * 256);
        }
        #pragma unroll
        for (int i = 0; i < 4; ++i) {        // B bf16: 8 chunks/row of 8 elems
            int flat = i * 2048 + wave * 512 + lane * 8;
            int r  = flat >> 6;
            int cc = (flat >> 3) & 7;
            int gc = (cc ^ (r & 7)) << 3;
            gload_lds16(Bt + (size_t)(col0 + r) * Dc + k0 + gc, Bs + i * 2048 + wave * 512);
        }
        __syncthreads();
        #pragma unroll
        for (int ks = 0; ks < 2; ++ks) {
            const int kc8 = ks * 4 + (lane >> 4);
            const int kc4 = kc8 << 1;
            bf16x8 av[4], bv[4];
            #pragma unroll
            for (int mi = 0; mi < 4; ++mi) {
                int r  = waveM * 64 + mi * 16 + (lane & 15);
                int r4 = r & 15;
                f32x4 lo = *(const f32x4*)&Asf[r * 64 + (((kc4    ) ^ r4) << 2)];
                f32x4 hi = *(const f32x4*)&Asf[r * 64 + (((kc4 + 1) ^ r4) << 2)];
                bf16x8 a;
                a[0] = (__bf16)lo[0]; a[1] = (__bf16)lo[1]; a[2] = (__bf16)lo[2]; a[3] = (__bf16)lo[3];
                a[4] = (__bf16)hi[0]; a[5] = (__bf16)hi[1]; a[6] = (__bf16)hi[2]; a[7] = (__bf16)hi[3];
                av[mi] = a;
            }
            #pragma unroll
            for (int ni = 0; ni < 4; ++ni) {
                int r = waveN * 64 + ni * 16 + (lane & 15);
                bv[ni] = *(const bf16x8*)&Bs[r * 64 + ((kc8 ^ (r & 7)) << 3)];
            }
            #pragma unroll
            for (int mi = 0; mi < 4; ++mi)
                #pragma unroll
                for (int ni = 0; ni < 4; ++ni)
                    acc[mi][ni] = mfma16x16x32(av[mi], bv[ni], acc[mi][ni]);
        }
        __syncthreads();
    }

    const int rb = (lane >> 4) << 2;
    const int cb = lane & 15;
    __bf16* T = (__bf16*)smem;               // [128][136] transpose staging
    #pragma unroll
    for (int mi = 0; mi < 4; ++mi)
        #pragma unroll
        for (int ni = 0; ni < 4; ++ni) {
            int lr = waveM * 64 + mi * 16 + rb;
            int lc = waveN * 64 + ni * 16 + cb;
            #pragma unroll
            for (int rr = 0; rr < 4; ++rr) {
                __bf16 h = (__bf16)acc[mi][ni][rr];
                Cb[(size_t)(row0 + lr + rr) * Dc + col0 + lc] = h;
                T[lc * 136 + lr + rr] = h;
            }
        }
    __syncthreads();
    const int bb = row0 >> 11;               // batch = global row / 2048
    const int s0 = row0 & 2047;
    #pragma unroll
    for (int i = 0; i < 8; ++i) {
        int n  = i * 16 + (tid >> 4);
        int mo = (tid & 15) * 8;
        bf16x8 v = *(const bf16x8*)&T[n * 136 + mo];
        *(bf16x8*)&CTb[(size_t)bb * Dc * Sc + (size_t)(col0 + n) * Sc + s0 + mo] = v;
    }
}

extern "C" void kernel_launch(void* const* d_in, const int* in_sizes, int n_in,
                              void* d_out, int out_size, void* d_ws, size_t ws_size,
                              hipStream_t stream)
{
    (void)in_sizes; (void)n_in; (void)out_size; (void)ws_size;
    const float* context = (const float*)d_in[0];
    const float* W_in    = (const float*)d_in[1];
    const float* W_out   = (const float*)d_in[2];
    float* out  = (float*)d_out;
    float* attn = out + (size_t)Bc * Sc * Dc;       // [B,S,S] fp32 output (written by PV)

    char* ws = (char*)d_ws;
    __bf16* c_bf    = (__bf16*)ws;                                 // [B*S, D]; later tanh(ctx)
    __bf16* cT_bf   = (__bf16*)(ws + 16777216);                    // [B, D, S]
    __bf16* wi_bf   = (__bf16*)(ws + 33554432);
    __bf16* wo_bf   = (__bf16*)(ws + 34078720);
    float2* stats   = (float2*)(ws + 34603008);                    // [B*S][32] {m, sumE}
    __bf16* Ebuf    = (__bf16*)(ws + 40894464);                    // [B][S][S] bf16

    // W -> bf16
    k_convert_w<<<dim3(Dc * Dc / 256), 256, 0, stream>>>(W_in, W_out, wi_bf, wo_bf);

    // c = context @ W_in^T  (also emits c^T)
    k_cproj<<<dim3(Dc / 128, (Bc * Sc) / 128), 256, 0, stream>>>(context, wi_bf, c_bf, cT_bf);

    // E = exp(scores - m_tile) bf16 + per-64-tile stats (XCD-batch-pinned)
    k_scores<<<dim3(Bc * 16 * 16), 256, 0, stream>>>(c_bf, Ebuf, stats);

    // PV (combine fused into prologue): attn = E*corr fp32 -> output;
    // ctx = tanh(attn @ c) bf16
    k_pv_fused<<<dim3((Sc / 64) * Bc), 512, 0, stream>>>(Ebuf, cT_bf, stats, attn, c_bf);

    // out = tanh(ctx) @ W_out^T
    k_gemm_bf16<<<dim3(Dc / 128, (Bc * Sc) / 128, 1), 256, 0, stream>>>(
        c_bf, wo_bf, out, Dc, Dc, Dc, Dc);
}

// Round 18
// 181.359 us; speedup vs baseline: 1.0347x; 1.0056x over previous
//
#include <hip/hip_runtime.h>
#include <cstdint>
#include <cstddef>

#define Bc 8
#define Sc 2048
#define Dc 512

typedef float f32x4 __attribute__((ext_vector_type(4)));
typedef __bf16 bf16x8 __attribute__((ext_vector_type(8)));
typedef __bf16 bf16x4 __attribute__((ext_vector_type(4)));

__device__ __forceinline__ void gload_lds16(const void* g, void* l) {
    __builtin_amdgcn_global_load_lds((const __attribute__((address_space(1))) void*)g,
                                     (__attribute__((address_space(3))) void*)l, 16, 0, 0);
}

__device__ __forceinline__ f32x4 mfma16x16x32(bf16x8 a, bf16x8 b, f32x4 c) {
    return __builtin_amdgcn_mfma_f32_16x16x32_bf16(a, b, c, 0, 0, 0);
}

// ---- convert W_in / W_out to bf16 (512*512 each) ----
__global__ void k_convert_w(const float* __restrict__ wi, const float* __restrict__ wo,
                            __bf16* __restrict__ wib, __bf16* __restrict__ wob) {
    int i = blockIdx.x * 256 + threadIdx.x;   // grid sized exactly Dc*Dc/256
    wib[i] = (__bf16)wi[i];
    wob[i] = (__bf16)wo[i];
}

// ---- scores kernel: 128x128x512 tile; emits E = exp(s - m_tile) bf16 plus
//      per-(row, 64-col-tile) stats {m_tile, sum E}. XCD-batch-pinned. ----
__global__ __launch_bounds__(256) void k_scores(
        const __bf16* __restrict__ c, __bf16* __restrict__ Ebuf,
        float2* __restrict__ stats)
{
    __shared__ alignas(16) char smem[34816];
    __bf16* As = (__bf16*)smem;
    __bf16* Bs = (__bf16*)(smem + 16384);
    const int tid  = threadIdx.x;
    const int wave = tid >> 6, lane = tid & 63;
    const int waveM = wave >> 1, waveN = wave & 1;
    const int bid  = blockIdx.x;
    const int bz   = bid & 7;
    const int col0 = ((bid >> 3) & 15) * 128;
    const int row0 = (bid >> 7) * 128;
    const __bf16* A  = c + (size_t)bz * Sc * Dc;

    f32x4 acc[4][4] = {};

    for (int k0 = 0; k0 < Dc; k0 += 64) {
        #pragma unroll
        for (int i = 0; i < 4; ++i) {
            int flat = i * 2048 + wave * 512 + lane * 8;
            int r  = flat >> 6;
            int cc = (flat >> 3) & 7;
            int gc = (cc ^ (r & 7)) << 3;
            gload_lds16(A + (size_t)(row0 + r) * Dc + k0 + gc, As + i * 2048 + wave * 512);
            gload_lds16(A + (size_t)(col0 + r) * Dc + k0 + gc, Bs + i * 2048 + wave * 512);
        }
        __syncthreads();
        #pragma unroll
        for (int ks = 0; ks < 2; ++ks) {
            const int kc = ks * 4 + (lane >> 4);
            bf16x8 av[4], bv[4];
            #pragma unroll
            for (int mi = 0; mi < 4; ++mi) {
                int r = waveM * 64 + mi * 16 + (lane & 15);
                av[mi] = *(const bf16x8*)&As[r * 64 + ((kc ^ (r & 7)) << 3)];
            }
            #pragma unroll
            for (int ni = 0; ni < 4; ++ni) {
                int r = waveN * 64 + ni * 16 + (lane & 15);
                bv[ni] = *(const bf16x8*)&Bs[r * 64 + ((kc ^ (r & 7)) << 3)];
            }
            #pragma unroll
            for (int mi = 0; mi < 4; ++mi)
                #pragma unroll
                for (int ni = 0; ni < 4; ++ni)
                    acc[mi][ni] = mfma16x16x32(av[mi], bv[ni], acc[mi][ni]);
        }
        __syncthreads();
    }

    const int rb = (lane >> 4) << 2;
    const int cb = lane & 15;
    __bf16* Es = (__bf16*)smem;                   // [128][136] bf16
    #pragma unroll
    for (int mi = 0; mi < 4; ++mi)
        #pragma unroll
        for (int rr = 0; rr < 4; ++rr) {
            float mx = fmaxf(fmaxf(acc[mi][0][rr], acc[mi][1][rr]),
                             fmaxf(acc[mi][2][rr], acc[mi][3][rr]));
            #pragma unroll
            for (int off = 1; off < 16; off <<= 1) mx = fmaxf(mx, __shfl_xor(mx, off));
            const int rloc = waveM * 64 + mi * 16 + rb + rr;
            float zs = 0.f;
            #pragma unroll
            for (int ni = 0; ni < 4; ++ni) {
                float e = __expf(acc[mi][ni][rr] - mx);
                zs += e;
                Es[rloc * 136 + waveN * 64 + ni * 16 + cb] = (__bf16)e;
            }
            #pragma unroll
            for (int off = 1; off < 16; off <<= 1) zs += __shfl_xor(zs, off);
            if ((lane & 15) == 0)
                stats[((size_t)bz * Sc + row0 + rloc) * 32 + (col0 >> 6) + waveN] =
                    make_float2(mx, zs);
        }
    __syncthreads();
    #pragma unroll
    for (int p = 0; p < 8; ++p) {
        int r  = p * 16 + (tid >> 4);
        int cc = (tid & 15) * 8;
        bf16x8 v = *(const bf16x8*)&Es[r * 136 + cc];
        *(bf16x8*)&Ebuf[((size_t)bz * Sc + row0 + r) * Sc + col0 + cc] = v;
    }
}

// ---- fused PV v11 (R16, session best): R12's counted-vmcnt schedule +
//      in-prologue softmax combine. 64 rows x 512 D-cols, 512 thr, 8 waves,
//      72 KiB LDS, grid 256 (1 block/CU, XCD-batch-pinned). ----
__global__ __launch_bounds__(512) void k_pv_fused(
        const __bf16* __restrict__ Ebuf,     // E [B][S][S] bf16
        const __bf16* __restrict__ cT,       // [B][D][S]
        const float2* __restrict__ stats,    // [B*S][32] {m, sumE}
        float* __restrict__ attn,            // [B][S][S] fp32 OUTPUT
        __bf16* __restrict__ ctx)            // [B*S][D] tanh(attn @ c)
{
    __shared__ alignas(16) __bf16 As[64 * 64];    //  8 KiB (P tile, swizzled)
    __shared__ alignas(16) __bf16 Bs[512 * 64];   // 64 KiB (cT K-slice)
    const int tid  = threadIdx.x;
    const int wave = tid >> 6, lane = tid & 63;
    const int b    = blockIdx.x & 7;              // == XCD id under %8 round-robin
    const int row0 = (blockIdx.x >> 3) * 64;
    const __bf16* Bt = cT + (size_t)b * Dc * Sc;

    const int ar = tid >> 3;            // 0..63
    const int ac = (tid & 7) * 8;       // 0..56
    const __bf16* erow = Ebuf + ((size_t)b * Sc + row0 + ar) * Sc + ac;
    const float*  srow_stats = (const float*)(stats + ((size_t)b * Sc + row0 + ar) * 32);
    float*        prow = attn + ((size_t)b * Sc + row0 + ar) * Sc + ac;
    const int a_addr = ar * 64 + (((ac >> 3) ^ (ar & 7)) << 3);

    // ---- fused combine: M = max m_i ; Z = sum z_i exp(m_i - M) ; zi = 1/Z ----
    f32x4 sb[16];                       // this row's 32 float2 stats (static-indexed)
    #pragma unroll
    for (int i = 0; i < 16; ++i) sb[i] = *(const f32x4*)&srow_stats[i * 4];
    float M = fmaxf(sb[0][0], sb[0][2]);
    #pragma unroll
    for (int i = 1; i < 16; ++i) M = fmaxf(M, fmaxf(sb[i][0], sb[i][2]));
    float Z = 0.f;
    #pragma unroll
    for (int i = 0; i < 16; ++i)
        Z += sb[i][1] * __expf(sb[i][0] - M) + sb[i][3] * __expf(sb[i][2] - M);
    const float zi = 1.f / Z;

    f32x4 acc[4][4] = {};               // wave tile: 64 rows x 64 cols
    const int NT = Sc / 64;             // 32 K-tiles

    auto stageB = [&](int kt) {         // [512][64] bf16 = 4096 chunks, 8 / thread
        #pragma unroll
        for (int i = 0; i < 8; ++i) {
            int chunk = i * 512 + tid;
            int r  = chunk >> 3;
            int cc = chunk & 7;
            gload_lds16(Bt + (size_t)r * Sc + kt + ((cc ^ (r & 7)) << 3),
                        Bs + (size_t)chunk * 8);
        }
    };

    // ---- prologue: P(0)->As + stage B(0); attn store(0) + E(1) in flight ----
    bf16x8 e = *(const bf16x8*)&erow[0];
    float  cf      = __expf(sb[0][0] - M) * zi;   // corr(0)
    float  sm_next = sb[0][2];                    // m(1), raw (transform at use)
    f32x4 p0, p1;
    #pragma unroll
    for (int j = 0; j < 4; ++j) { p0[j] = (float)e[j] * cf; p1[j] = (float)e[4 + j] * cf; }
    {
        bf16x8 pb;
        #pragma unroll
        for (int j = 0; j < 4; ++j) { pb[j] = (__bf16)p0[j]; pb[4 + j] = (__bf16)p1[j]; }
        *(bf16x8*)&As[a_addr] = pb;                          // lgkm +1
    }
    stageB(0);                                               // vm +8 (oldest)
    __builtin_amdgcn_sched_barrier(0);                       // pin younger vmem after stage
    *(f32x4*)&prow[0] = p0;                                  // vm +1
    *(f32x4*)&prow[4] = p1;                                  // vm +1
    e = *(const bf16x8*)&erow[64];                           // vm +1
    asm volatile("s_waitcnt vmcnt(3) lgkmcnt(0)" ::: "memory");  // 8 stage + As done
    __builtin_amdgcn_sched_barrier(0);
    __builtin_amdgcn_s_barrier();

    for (int t = 0; t < NT; ++t) {
        bf16x8 av[4][2], bv[2][4];
        #pragma unroll
        for (int ks = 0; ks < 2; ++ks) {
            const int kc = ks * 4 + (lane >> 4);
            #pragma unroll
            for (int mi = 0; mi < 4; ++mi) {
                int r = mi * 16 + (lane & 15);
                av[mi][ks] = *(const bf16x8*)&As[r * 64 + ((kc ^ (r & 7)) << 3)];
            }
            #pragma unroll
            for (int ni = 0; ni < 4; ++ni) {
                int r = wave * 64 + ni * 16 + (lane & 15);
                bv[ks][ni] = *(const bf16x8*)&Bs[r * 64 + ((kc ^ (r & 7)) << 3)];
            }
        }
        asm volatile("s_waitcnt lgkmcnt(0)" ::: "memory");
        __builtin_amdgcn_sched_barrier(0);
        __builtin_amdgcn_s_barrier();

        if (t + 1 < NT) {
            stageB((t + 1) * 64);                            // vm +8
            __builtin_amdgcn_sched_barrier(0);
            const float cfv = __expf(sm_next - M) * zi;      // corr(t+1)
            f32x4 q0, q1;
            #pragma unroll
            for (int j = 0; j < 4; ++j) {
                q0[j] = (float)e[j] * cfv; q1[j] = (float)e[4 + j] * cfv;
            }
            bf16x8 pb;
            #pragma unroll
            for (int j = 0; j < 4; ++j) { pb[j] = (__bf16)q0[j]; pb[4 + j] = (__bf16)q1[j]; }
            *(bf16x8*)&As[a_addr] = pb;                      // lgkm +1
            *(f32x4*)&prow[(t + 1) * 64]     = q0;           // vm +1
            *(f32x4*)&prow[(t + 1) * 64 + 4] = q1;           // vm +1
            if (t + 2 < NT) {
                e       = *(const bf16x8*)&erow[(t + 2) * 64];   // vm +1
                sm_next = srow_stats[(t + 2) * 2];               // vm +1 (m, raw)
            }
        }

        #pragma unroll
        for (int ks = 0; ks < 2; ++ks)
            #pragma unroll
            for (int mi = 0; mi < 4; ++mi)
                #pragma unroll
                for (int ni = 0; ni < 4; ++ni)
                    acc[mi][ni] = mfma16x16x32(av[mi][ks], bv[ks][ni], acc[mi][ni]);

        if (t + 1 < NT) {
            if (t + 2 < NT)
                asm volatile("s_waitcnt vmcnt(4) lgkmcnt(0)" ::: "memory");
            else
                asm volatile("s_waitcnt vmcnt(2) lgkmcnt(0)" ::: "memory");
            __builtin_amdgcn_sched_barrier(0);
            __builtin_amdgcn_s_barrier();
        }
    }

    const int rb = (lane >> 4) << 2;
    const int cb = lane & 15;
    #pragma unroll
    for (int mi = 0; mi < 4; ++mi)
        #pragma unroll
        for (int ni = 0; ni < 4; ++ni) {
            int gr = row0 + mi * 16 + rb;
            int gc = wave * 64 + ni * 16 + cb;
            #pragma unroll
            for (int rr = 0; rr < 4; ++rr)
                ctx[(size_t)(b * Sc + gr + rr) * Dc + gc] = (__bf16)tanhf(acc[mi][ni][rr]);
        }
}

// ---- bf16 GEMM (out-projection): C fp32 = A[M,K] * Bt[N,K]^T, 128x128x64 ----
__global__ __launch_bounds__(256) void k_gemm_bf16(
        const __bf16* __restrict__ A, const __bf16* __restrict__ Bt,
        float* __restrict__ C, int lda, int ldb, int ldc, int K)
{
    __shared__ alignas(16) __bf16 smem[2 * 128 * 64];
    __bf16* As = smem;
    __bf16* Bs = smem + 128 * 64;
    const int tid  = threadIdx.x;
    const int wave = tid >> 6, lane = tid & 63;
    const int waveM = wave >> 1, waveN = wave & 1;
    const int row0 = blockIdx.y * 128;
    const int col0 = blockIdx.x * 128;

    f32x4 acc[4][4] = {};

    for (int k0 = 0; k0 < K; k0 += 64) {
        #pragma unroll
        for (int i = 0; i < 4; ++i) {
            int flat = i * 2048 + wave * 512 + lane * 8;
            int r  = flat >> 6;
            int cc = (flat >> 3) & 7;
            int gc = (cc ^ (r & 7)) << 3;
            gload_lds16(A  + (size_t)(row0 + r) * lda + k0 + gc, As + i * 2048 + wave * 512);
            gload_lds16(Bt + (size_t)(col0 + r) * ldb + k0 + gc, Bs + i * 2048 + wave * 512);
        }
        __syncthreads();
        #pragma unroll
        for (int ks = 0; ks < 2; ++ks) {
            const int kc = ks * 4 + (lane >> 4);
            bf16x8 av[4], bv[4];
            #pragma unroll
            for (int mi = 0; mi < 4; ++mi) {
                int r = waveM * 64 + mi * 16 + (lane & 15);
                av[mi] = *(const bf16x8*)&As[r * 64 + ((kc ^ (r & 7)) << 3)];
            }
            #pragma unroll
            for (int ni = 0; ni < 4; ++ni) {
                int r = waveN * 64 + ni * 16 + (lane & 15);
                bv[ni] = *(const bf16x8*)&Bs[r * 64 + ((kc ^ (r & 7)) << 3)];
            }
            #pragma unroll
            for (int mi = 0; mi < 4; ++mi)
                #pragma unroll
                for (int ni = 0; ni < 4; ++ni)
                    acc[mi][ni] = mfma16x16x32(av[mi], bv[ni], acc[mi][ni]);
        }
        __syncthreads();
    }

    const int rb = (lane >> 4) << 2;
    const int cb = lane & 15;
    #pragma unroll
    for (int mi = 0; mi < 4; ++mi)
        #pragma unroll
        for (int ni = 0; ni < 4; ++ni) {
            int gr = row0 + waveM * 64 + mi * 16 + rb;
            int gc = col0 + waveN * 64 + ni * 16 + cb;
            #pragma unroll
            for (int rr = 0; rr < 4; ++rr)
                C[(size_t)(gr + rr) * ldc + gc] = acc[mi][ni][rr];
        }
}

// ---- fp32-A, bf16-B GEMM (c-projection): writes bf16 C and bf16 C^T ----
__global__ __launch_bounds__(256) void k_cproj(
        const float* __restrict__ A, const __bf16* __restrict__ Bt,
        __bf16* __restrict__ Cb, __bf16* __restrict__ CTb)
{
    __shared__ alignas(16) char smem[49152];
    float*  Asf = (float*)smem;              // [128][64] fp32 (32 KiB)
    __bf16* Bs  = (__bf16*)(smem + 32768);   // [128][64] bf16 (16 KiB)
    const int tid  = threadIdx.x;
    const int wave = tid >> 6, lane = tid & 63;
    const int waveM = wave >> 1, waveN = wave & 1;
    const int row0 = blockIdx.y * 128;
    const int col0 = blockIdx.x * 128;

    f32x4 acc[4][4] = {};

    for (int k0 = 0; k0 < Dc; k0 += 64) {
        #pragma unroll
        for (int i = 0; i < 8; ++i) {        // A fp32: 16 chunks/row of 4 floats
            int flat = i * 1024 + wave * 256 + lane * 4;
            int r  = flat >> 6;
            int cc = (flat >> 2) & 15;
            int gc = (cc ^ (r & 15)) << 2;
            gload_lds16(A + (size_t)(row0 + r) * Dc + k0 + gc, Asf + i * 1024 + wave * 256);
        }
        #pragma unroll
        for (int i = 0; i < 4; ++i) {        // B bf16: 8 chunks/row of 8 elems
            int flat = i * 2048 + wave * 512 + lane * 8;
            int r  = flat >> 6;
            int cc = (flat >> 3) & 7;
            int gc = (cc ^ (r & 7)) << 3;
            gload_lds16(Bt + (size_t)(col0 + r) * Dc + k0 + gc, Bs + i * 2048 + wave * 512);
        }
        __syncthreads();
        #pragma unroll
        for (int ks = 0; ks < 2; ++ks) {
            const int kc8 = ks * 4 + (lane >> 4);
            const int kc4 = kc8 << 1;
            bf16x8 av[4], bv[4];
            #pragma unroll
            for (int mi = 0; mi < 4; ++mi) {
                int r  = waveM * 64 + mi * 16 + (lane & 15);
                int r4 = r & 15;
                f32x4 lo = *(const f32x4*)&Asf[r * 64 + (((kc4    ) ^ r4) << 2)];
                f32x4 hi = *(const f32x4*)&Asf[r * 64 + (((kc4 + 1) ^ r4) << 2)];
                bf16x8 a;
                a[0] = (__bf16)lo[0]; a[1] = (__bf16)lo[1]; a[2] = (__bf16)lo[2]; a[3] = (__bf16)lo[3];
                a[4] = (__bf16)hi[0]; a[5] = (__bf16)hi[1]; a[6] = (__bf16)hi[2]; a[7] = (__bf16)hi[3];
                av[mi] = a;
            }
            #pragma unroll
            for (int ni = 0; ni < 4; ++ni) {
                int r = waveN * 64 + ni * 16 + (lane & 15);
                bv[ni] = *(const bf16x8*)&Bs[r * 64 + ((kc8 ^ (r & 7)) << 3)];
            }
            #pragma unroll
            for (int mi = 0; mi < 4; ++mi)
                #pragma unroll
                for (int ni = 0; ni < 4; ++ni)
                    acc[mi][ni] = mfma16x16x32(av[mi], bv[ni], acc[mi][ni]);
        }
        __syncthreads();
    }

    const int rb = (lane >> 4) << 2;
    const int cb = lane & 15;
    __bf16* T = (__bf16*)smem;               // [128][136] transpose staging
    #pragma unroll
    for (int mi = 0; mi < 4; ++mi)
        #pragma unroll
        for (int ni = 0; ni < 4; ++ni) {
            int lr = waveM * 64 + mi * 16 + rb;
            int lc = waveN * 64 + ni * 16 + cb;
            #pragma unroll
            for (int rr = 0; rr < 4; ++rr) {
                __bf16 h = (__bf16)acc[mi][ni][rr];
                Cb[(size_t)(row0 + lr + rr) * Dc + col0 + lc] = h;
                T[lc * 136 + lr + rr] = h;
            }
        }
    __syncthreads();
    const int bb = row0 >> 11;               // batch = global row / 2048
    const int s0 = row0 & 2047;
    #pragma unroll
    for (int i = 0; i < 8; ++i) {
        int n  = i * 16 + (tid >> 4);
        int mo = (tid & 15) * 8;
        bf16x8 v = *(const bf16x8*)&T[n * 136 + mo];
        *(bf16x8*)&CTb[(size_t)bb * Dc * Sc + (size_t)(col0 + n) * Sc + s0 + mo] = v;
    }
}

extern "C" void kernel_launch(void* const* d_in, const int* in_sizes, int n_in,
                              void* d_out, int out_size, void* d_ws, size_t ws_size,
                              hipStream_t stream)
{
    (void)in_sizes; (void)n_in; (void)out_size; (void)ws_size;
    const float* context = (const float*)d_in[0];
    const float* W_in    = (const float*)d_in[1];
    const float* W_out   = (const float*)d_in[2];
    float* out  = (float*)d_out;
    float* attn = out + (size_t)Bc * Sc * Dc;       // [B,S,S] fp32 output (written by PV)

    char* ws = (char*)d_ws;
    __bf16* c_bf    = (__bf16*)ws;                                 // [B*S, D]; later tanh(ctx)
    __bf16* cT_bf   = (__bf16*)(ws + 16777216);                    // [B, D, S]
    __bf16* wi_bf   = (__bf16*)(ws + 33554432);
    __bf16* wo_bf   = (__bf16*)(ws + 34078720);
    float2* stats   = (float2*)(ws + 34603008);                    // [B*S][32] {m, sumE}
    __bf16* Ebuf    = (__bf16*)(ws + 40894464);                    // [B][S][S] bf16

    // W -> bf16
    k_convert_w<<<dim3(Dc * Dc / 256), 256, 0, stream>>>(W_in, W_out, wi_bf, wo_bf);

    // c = context @ W_in^T  (also emits c^T)
    k_cproj<<<dim3(Dc / 128, (Bc * Sc) / 128), 256, 0, stream>>>(context, wi_bf, c_bf, cT_bf);

    // E = exp(scores - m_tile) bf16 + per-64-tile stats (XCD-batch-pinned)
    k_scores<<<dim3(Bc * 16 * 16), 256, 0, stream>>>(c_bf, Ebuf, stats);

    // PV (combine fused into prologue): attn = E*corr fp32 -> output;
    // ctx = tanh(attn @ c) bf16
    k_pv_fused<<<dim3((Sc / 64) * Bc), 512, 0, stream>>>(Ebuf, cT_bf, stats, attn, c_bf);

    // out = tanh(ctx) @ W_out^T
    k_gemm_bf16<<<dim3(Dc / 128, (Bc * Sc) / 128, 1), 256, 0, stream>>>(
        c_bf, wo_bf, out, Dc, Dc, Dc, Dc);
}